// Round 1
// 1384.339 us; speedup vs baseline: 1.2443x; 1.2443x over previous
//
#include <hip/hip_runtime.h>
#include <cstddef>

#define HIDDEN 128

typedef __bf16 bf16x8 __attribute__((ext_vector_type(8)));
typedef float  f32x4  __attribute__((ext_vector_type(4)));

__device__ inline unsigned short bf16_rne(float x) {
    unsigned u = __float_as_uint(x);
    u += 0x7FFFu + ((u >> 16) & 1u);
    return (unsigned short)(u >> 16);
}

// ---------------------------------------------------------------------------
// Generic row-block GEMM: OUT(nrows x COLS) = IN(nrows x 128) @ W(128 x COLS)
// 64 rows per block, 256 threads. Thread (rg,cg): rows rg*8..+7, cols cg*CPT..
// ---------------------------------------------------------------------------
template <int COLS>
__global__ __launch_bounds__(256, 2) void rowgemm_kernel(
    const float* __restrict__ in, const float* __restrict__ W,
    float* __restrict__ out, int nrows)
{
    constexpr int CPT = COLS / 32;  // 4 or 8 cols per thread
    __shared__ float ldsA[64 * HIDDEN];  // 32 KB
    const int row0 = blockIdx.x * 64;
    const int t = threadIdx.x;

    {   // stage 64x128 row tile (zero-pad past nrows); fully coalesced
        const float4* in4 = (const float4*)in;
        float4* lds4 = (float4*)ldsA;
#pragma unroll
        for (int s = 0; s < 8; ++s) {
            int idx = t + s * 256;          // float4 index within tile
            int r = idx >> 5;               // 32 float4 per row
            int grow = row0 + r;
            float4 v = make_float4(0.f, 0.f, 0.f, 0.f);
            if (grow < nrows) v = in4[(size_t)grow * 32 + (idx & 31)];
            lds4[idx] = v;
        }
    }
    __syncthreads();

    const int cg = t & 31, rg = t >> 5;
    float4 acc0[8], acc1[8];
#pragma unroll
    for (int i = 0; i < 8; ++i) {
        acc0[i] = make_float4(0.f, 0.f, 0.f, 0.f);
        if constexpr (CPT == 8) acc1[i] = make_float4(0.f, 0.f, 0.f, 0.f);
    }
    const float4* lds4 = (const float4*)ldsA;
    const float4* W4 = (const float4*)W;

    for (int k4 = 0; k4 < 32; ++k4) {
        float4 a[8];
#pragma unroll
        for (int i = 0; i < 8; ++i) a[i] = lds4[(rg * 8 + i) * 32 + k4];
#pragma unroll
        for (int kk = 0; kk < 4; ++kk) {
            const int k = k4 * 4 + kk;
            float4 b0 = W4[(k * COLS + cg * CPT) >> 2];
            float4 b1;
            if constexpr (CPT == 8) b1 = W4[((k * COLS + cg * CPT) >> 2) + 1];
#pragma unroll
            for (int i = 0; i < 8; ++i) {
                const float av = (kk == 0) ? a[i].x : (kk == 1) ? a[i].y
                               : (kk == 2) ? a[i].z : a[i].w;
                acc0[i].x = fmaf(av, b0.x, acc0[i].x);
                acc0[i].y = fmaf(av, b0.y, acc0[i].y);
                acc0[i].z = fmaf(av, b0.z, acc0[i].z);
                acc0[i].w = fmaf(av, b0.w, acc0[i].w);
                if constexpr (CPT == 8) {
                    acc1[i].x = fmaf(av, b1.x, acc1[i].x);
                    acc1[i].y = fmaf(av, b1.y, acc1[i].y);
                    acc1[i].z = fmaf(av, b1.z, acc1[i].z);
                    acc1[i].w = fmaf(av, b1.w, acc1[i].w);
                }
            }
        }
    }

#pragma unroll
    for (int i = 0; i < 8; ++i) {
        int grow = row0 + rg * 8 + i;
        if (grow < nrows) {
            float4* o4 = (float4*)(out + (size_t)grow * COLS + cg * CPT);
            o4[0] = acc0[i];
            if constexpr (CPT == 8) o4[1] = acc1[i];
        }
    }
}

// ---------------------------------------------------------------------------
// Wb prep: transpose + split fp32 -> bf16 hi/lo.  WbT[col][k], col<256, k<128.
// ---------------------------------------------------------------------------
__global__ __launch_bounds__(256) void wb_prep_kernel(
    const float* __restrict__ Wb,
    unsigned short* __restrict__ hi, unsigned short* __restrict__ lo)
{
    int id = blockIdx.x * 256 + threadIdx.x;
    if (id >= 128 * 256) return;
    int col = id >> 7;      // 0..255
    int k = id & 127;       // 0..127
    float x = Wb[(size_t)k * 256 + col];
    unsigned short h = bf16_rne(x);
    float hf = __uint_as_float((unsigned)h << 16);
    unsigned short l = bf16_rne(x - hf);
    hi[(size_t)col * 128 + k] = h;
    lo[(size_t)col * 128 + k] = l;
}

// ---------------------------------------------------------------------------
// Fused edge kernel (MFMA): b = IR@Wb via bf16 hi/lo 3-term split on the
// matrix pipe, then per-edge logits.
//   logit[m,h] = sum_d qg[c]*(kg[c]*(1+bm[c]) + ba[c]) / norm, c = d*8+h
// 64 edges/block, 4 waves; wave w owns output cols [w*64, w*64+64).
// bm/ba exchanged through a 33 KB transposed LDS buffer in two passes.
// ---------------------------------------------------------------------------
__global__ __launch_bounds__(256, 2) void edge_logit_mfma_kernel(
    const float* __restrict__ ir,
    const unsigned short* __restrict__ WbT_hi,
    const unsigned short* __restrict__ WbT_lo,
    const float* __restrict__ qtab, const float* __restrict__ kvtab,
    const int* __restrict__ qidx, const int* __restrict__ kidx,
    const float* __restrict__ normalizer,
    float* __restrict__ pair_logits, int M)
{
    // union: bf16 staging (2 x 16 KB) then transposed acc (128 x 65 f = 33280 B)
    __shared__ unsigned char smem[33280];
    unsigned short* lds_hi = (unsigned short*)smem;            // 64*128
    unsigned short* lds_lo = (unsigned short*)(smem + 16384);  // 64*128
    float* accT = (float*)smem;                                // [128][65]

    const int row0 = blockIdx.x * 64;
    const int t = threadIdx.x;
    const int w = t >> 6;        // wave 0..3
    const int lane = t & 63;
    const int arow = lane & 15;  // fragment row/col within 16
    const int kg = lane >> 4;    // k-group 0..3

    // epilogue identity (issue index loads early)
    const int e_ep = w * 16 + (lane >> 2);   // edge 0..63
    const int cb = lane & 3;                 // channel block 0..3 (32 ch each)
    const int m_ep = row0 + e_ep;
    int qi = 0, ki = 0;
    if (m_ep < M) { qi = qidx[m_ep]; ki = kidx[m_ep]; }

    // ---- stage IR tile, split fp32 -> bf16 hi/lo, XOR-swizzled ----------
    {
        const float4* in4 = (const float4*)ir;
#pragma unroll
        for (int s = 0; s < 8; ++s) {
            int idx = t + s * 256;          // float4 index within 64x128 tile
            int r = idx >> 5;
            int k4 = (idx & 31) * 4;
            float4 v = make_float4(0.f, 0.f, 0.f, 0.f);
            int grow = row0 + r;
            if (grow < M) v = in4[(size_t)grow * 32 + (idx & 31)];
            float xs[4] = {v.x, v.y, v.z, v.w};
            unsigned short h[4], l[4];
#pragma unroll
            for (int j = 0; j < 4; ++j) {
                h[j] = bf16_rne(xs[j]);
                float hf = __uint_as_float((unsigned)h[j] << 16);
                l[j] = bf16_rne(xs[j] - hf);
            }
            int elem = r * 128 + k4;
            int swz = elem ^ ((r & 7) << 3);   // bank-conflict swizzle (G4)
            *reinterpret_cast<uint2*>(lds_hi + swz) =
                make_uint2(h[0] | ((unsigned)h[1] << 16), h[2] | ((unsigned)h[3] << 16));
            *reinterpret_cast<uint2*>(lds_lo + swz) =
                make_uint2(l[0] | ((unsigned)l[1] << 16), l[2] | ((unsigned)l[3] << 16));
        }
    }
    __syncthreads();

    // ---- K loop: 4 steps of K=32, 16 frags/wave, 3-term split -----------
    f32x4 acc[4][4];
#pragma unroll
    for (int rt = 0; rt < 4; ++rt)
#pragma unroll
        for (int ct = 0; ct < 4; ++ct)
            acc[rt][ct] = (f32x4){0.f, 0.f, 0.f, 0.f};

#pragma unroll
    for (int ks = 0; ks < 4; ++ks) {
        const int k0 = ks * 32 + kg * 8;
        bf16x8 ah[4], al[4], bh[4], bl[4];
#pragma unroll
        for (int rt = 0; rt < 4; ++rt) {
            int row = rt * 16 + arow;
            int elem = row * 128 + k0;
            int swz = elem ^ ((row & 7) << 3);
            ah[rt] = *reinterpret_cast<const bf16x8*>(lds_hi + swz);
            al[rt] = *reinterpret_cast<const bf16x8*>(lds_lo + swz);
        }
#pragma unroll
        for (int ct = 0; ct < 4; ++ct) {
            size_t off = (size_t)(w * 64 + ct * 16 + arow) * 128 + k0;
            bh[ct] = *reinterpret_cast<const bf16x8*>(WbT_hi + off);
            bl[ct] = *reinterpret_cast<const bf16x8*>(WbT_lo + off);
        }
#pragma unroll
        for (int rt = 0; rt < 4; ++rt)
#pragma unroll
            for (int ct = 0; ct < 4; ++ct) {
                acc[rt][ct] = __builtin_amdgcn_mfma_f32_16x16x32_bf16(
                    ah[rt], bh[ct], acc[rt][ct], 0, 0, 0);
                acc[rt][ct] = __builtin_amdgcn_mfma_f32_16x16x32_bf16(
                    al[rt], bh[ct], acc[rt][ct], 0, 0, 0);
                acc[rt][ct] = __builtin_amdgcn_mfma_f32_16x16x32_bf16(
                    ah[rt], bl[ct], acc[rt][ct], 0, 0, 0);
            }
    }

    const float nvn = fminf(fmaxf(normalizer[0], 1.0f), 16.0f);
    const float invnorm = 1.0f / nvn;

    // ---- pass 1: waves 0,1 publish bm (cols 0..127) ---------------------
    __syncthreads();
    if (w < 2) {
#pragma unroll
        for (int rt = 0; rt < 4; ++rt)
#pragma unroll
            for (int ct = 0; ct < 4; ++ct) {
                int c = w * 64 + ct * 16 + arow;
                int eb = rt * 16 + kg * 4;
#pragma unroll
                for (int r = 0; r < 4; ++r)
                    accT[c * 65 + eb + r] = acc[rt][ct][r];
            }
    }
    __syncthreads();

    float4 qv[8];
    float hacc[8] = {0.f, 0.f, 0.f, 0.f, 0.f, 0.f, 0.f, 0.f};
    const float* qrow = qtab + (size_t)qi * 128 + cb * 32;
    const float* krow = kvtab + (size_t)ki * 256 + cb * 32;
    if (m_ep < M) {
#pragma unroll
        for (int j4 = 0; j4 < 8; ++j4)
            qv[j4] = *(const float4*)(qrow + j4 * 4);
#pragma unroll
        for (int j4 = 0; j4 < 8; ++j4) {
            float4 kv = *(const float4*)(krow + j4 * 4);
            int cl = cb * 32 + j4 * 4;                 // channel 0..127
            const float* bp = accT + cl * 65 + e_ep;
            int hb = (j4 & 1) * 4;                     // head base: (4*j4)&7
            float t0 = fmaf(kv.x, bp[0],   kv.x);      // k*(1+bm)
            float t1 = fmaf(kv.y, bp[65],  kv.y);
            float t2 = fmaf(kv.z, bp[130], kv.z);
            float t3 = fmaf(kv.w, bp[195], kv.w);
            hacc[hb + 0] = fmaf(qv[j4].x, t0, hacc[hb + 0]);
            hacc[hb + 1] = fmaf(qv[j4].y, t1, hacc[hb + 1]);
            hacc[hb + 2] = fmaf(qv[j4].z, t2, hacc[hb + 2]);
            hacc[hb + 3] = fmaf(qv[j4].w, t3, hacc[hb + 3]);
        }
    }
    __syncthreads();

    // ---- pass 2: waves 2,3 publish ba (cols 128..255) -------------------
    if (w >= 2) {
#pragma unroll
        for (int rt = 0; rt < 4; ++rt)
#pragma unroll
            for (int ct = 0; ct < 4; ++ct) {
                int c = (w - 2) * 64 + ct * 16 + arow;
                int eb = rt * 16 + kg * 4;
#pragma unroll
                for (int r = 0; r < 4; ++r)
                    accT[c * 65 + eb + r] = acc[rt][ct][r];
            }
    }
    __syncthreads();

    if (m_ep < M) {
#pragma unroll
        for (int j4 = 0; j4 < 8; ++j4) {
            int cl = cb * 32 + j4 * 4;
            const float* bp = accT + cl * 65 + e_ep;
            int hb = (j4 & 1) * 4;
            hacc[hb + 0] = fmaf(qv[j4].x, bp[0],   hacc[hb + 0]);   // q*ba
            hacc[hb + 1] = fmaf(qv[j4].y, bp[65],  hacc[hb + 1]);
            hacc[hb + 2] = fmaf(qv[j4].z, bp[130], hacc[hb + 2]);
            hacc[hb + 3] = fmaf(qv[j4].w, bp[195], hacc[hb + 3]);
        }
    }

    // reduce across the 4 cb lanes of this edge
#pragma unroll
    for (int j = 0; j < 8; ++j) {
        hacc[j] += __shfl_xor(hacc[j], 1);
        hacc[j] += __shfl_xor(hacc[j], 2);
    }
    if (m_ep < M) {
        if (cb == 0) {
            *(float4*)(pair_logits + (size_t)m_ep * 8) =
                make_float4(hacc[0] * invnorm, hacc[1] * invnorm,
                            hacc[2] * invnorm, hacc[3] * invnorm);
        } else if (cb == 1) {
            *(float4*)(pair_logits + (size_t)m_ep * 8 + 4) =
                make_float4(hacc[4] * invnorm, hacc[5] * invnorm,
                            hacc[6] * invnorm, hacc[7] * invnorm);
        }
    }
}

// ---------------------------------------------------------------------------
// CSR build: histogram -> block scan -> placement
// ---------------------------------------------------------------------------
__global__ __launch_bounds__(256) void hist_kernel(
    const int* __restrict__ qidx, int* __restrict__ cnt, int M)
{
    int m = blockIdx.x * 256 + threadIdx.x;
    if (m < M) atomicAdd(&cnt[qidx[m]], 1);
}

__global__ __launch_bounds__(256) void scan_kernel(
    const int* __restrict__ cnt, int* __restrict__ rowptr,
    int* __restrict__ wptr, int N)
{
    __shared__ int sums[256];
    const int t = threadIdx.x;
    const int chunk = (N + 255) / 256;
    const int b = t * chunk;
    const int e = min(b + chunk, N);
    int s = 0;
    for (int i = b; i < e; ++i) s += cnt[i];
    sums[t] = s;
    __syncthreads();
    for (int off = 1; off < 256; off <<= 1) {
        int v = (t >= off) ? sums[t - off] : 0;
        __syncthreads();
        sums[t] += v;
        __syncthreads();
    }
    int run = (t == 0) ? 0 : sums[t - 1];
    for (int i = b; i < e; ++i) {
        rowptr[i] = run;
        wptr[i] = run;
        run += cnt[i];
    }
    if (t == 255) rowptr[N] = sums[255];
}

__global__ __launch_bounds__(256) void place_kernel(
    const int* __restrict__ qidx, int* __restrict__ wptr,
    int* __restrict__ csr, int M)
{
    int m = blockIdx.x * 256 + threadIdx.x;
    if (m < M) {
        int p = atomicAdd(&wptr[qidx[m]], 1);
        csr[p] = m;
    }
}

// ---------------------------------------------------------------------------
// Per-node softmax + weighted V aggregation. One wave per node, no atomics.
// ---------------------------------------------------------------------------
__global__ __launch_bounds__(256) void node_agg_kernel(
    const float* __restrict__ pl, const float* __restrict__ kvtab,
    const int* __restrict__ kidx, const int* __restrict__ rowptr,
    const int* __restrict__ csr, float* __restrict__ agg, int N)
{
    const int node = blockIdx.x * 4 + (threadIdx.x >> 6);
    if (node >= N) return;
    const int lane = threadIdx.x & 63;
    const int h = lane & 7;
    const int beg = rowptr[node], end = rowptr[node + 1];

    float s = 0.f;
    for (int e = beg; e < end; ++e) {
        int m = csr[e];
        s += __expf(pl[(size_t)m * 8 + h]);
    }
    const float inv = 1.0f / s;

    float acc0 = 0.f, acc1 = 0.f;
    for (int e = beg; e < end; ++e) {
        int m = csr[e];
        float w = __expf(pl[(size_t)m * 8 + h]) * inv;
        const float* vp = kvtab + (size_t)kidx[m] * 256 + 128;
        acc0 = fmaf(w, vp[lane], acc0);
        acc1 = fmaf(w, vp[lane + 64], acc1);
    }
    agg[(size_t)node * 128 + lane] = acc0;
    agg[(size_t)node * 128 + 64 + lane] = acc1;
}

// ---------------------------------------------------------------------------
extern "C" void kernel_launch(void* const* d_in, const int* in_sizes, int n_in,
                              void* d_out, int out_size, void* d_ws, size_t ws_size,
                              hipStream_t stream)
{
    const float* query = (const float*)d_in[0];
    const float* key   = (const float*)d_in[1];
    const float* ir    = (const float*)d_in[2];
    const int*   qidx  = (const int*)d_in[3];
    const int*   kidx  = (const int*)d_in[4];
    const float* Wq    = (const float*)d_in[5];
    const float* Wkv   = (const float*)d_in[6];
    const float* Wb    = (const float*)d_in[7];
    const float* Wo    = (const float*)d_in[8];
    const float* normalizer = (const float*)d_in[9];

    const int N = in_sizes[0] / HIDDEN;   // 50000
    const int M = in_sizes[3];            // 800000

    float* out_result  = (float*)d_out;                        // N*128
    float* pair_logits = (float*)d_out + (size_t)N * HIDDEN;   // M*8

    // qtab borrows the out_result region (dead until the final GEMM).
    float* qtab = out_result;

    // workspace layout: agg(N*128 f, cnt aliases its head) | kvtab(N*256 f)
    //                   | rowptr(N+1 i) | wptr(N i) | csr(M i)   ~= 80 MB
    float* agg    = (float*)d_ws;
    int*   cnt    = (int*)d_ws;                          // dead before agg lives
    float* kvtab  = agg + (size_t)N * 128;
    int*   rowptr = (int*)(kvtab + (size_t)N * 256);
    int*   wptr   = rowptr + (N + 1);
    int*   csr    = wptr + N;

    // WbT hi/lo (bf16, 64 KB each) parked mid-agg: past cnt's head usage,
    // dead only after edge kernel; node_agg overwrites later (stream-ordered).
    unsigned short* WbT_hi = (unsigned short*)(agg + (size_t)N * 64);
    unsigned short* WbT_lo = WbT_hi + 256 * 128;

    const int rgrid = (N + 63) / 64;
    const int mgrid = (M + 255) / 256;

    // Wb transpose + bf16 split (tiny)
    wb_prep_kernel<<<128, 256, 0, stream>>>(Wb, WbT_hi, WbT_lo);

    // CSR build
    hipMemsetAsync(cnt, 0, (size_t)N * sizeof(int), stream);
    hist_kernel<<<mgrid, 256, 0, stream>>>(qidx, cnt, M);
    scan_kernel<<<1, 256, 0, stream>>>(cnt, rowptr, wptr, N);
    place_kernel<<<mgrid, 256, 0, stream>>>(qidx, wptr, csr, M);

    // projections
    rowgemm_kernel<128><<<rgrid, 256, 0, stream>>>(query, Wq, qtab, N);
    rowgemm_kernel<256><<<rgrid, 256, 0, stream>>>(key, Wkv, kvtab, N);

    // fused b-GEMM (MFMA, bf16x3 split) + per-edge logits
    edge_logit_mfma_kernel<<<(M + 63) / 64, 256, 0, stream>>>(
        ir, WbT_hi, WbT_lo, qtab, kvtab, qidx, kidx, normalizer,
        pair_logits, M);

    // per-node softmax + V aggregation (no atomics)
    node_agg_kernel<<<(N + 3) / 4, 256, 0, stream>>>(
        pair_logits, kvtab, kidx, rowptr, csr, agg, N);

    // output projection
    rowgemm_kernel<128><<<rgrid, 256, 0, stream>>>(agg, Wo, out_result, N);
}

// Round 2
// 1178.993 us; speedup vs baseline: 1.4610x; 1.1742x over previous
//
#include <hip/hip_runtime.h>
#include <cstddef>

#define HIDDEN 128

typedef _Float16 f16x8 __attribute__((ext_vector_type(8)));
typedef float    f32x4 __attribute__((ext_vector_type(4)));

// ---------------------------------------------------------------------------
// Generic row-block GEMM: OUT(nrows x COLS) = IN(nrows x 128) @ W(128 x COLS)
// ---------------------------------------------------------------------------
template <int COLS>
__global__ __launch_bounds__(256, 2) void rowgemm_kernel(
    const float* __restrict__ in, const float* __restrict__ W,
    float* __restrict__ out, int nrows)
{
    constexpr int CPT = COLS / 32;
    __shared__ float ldsA[64 * HIDDEN];
    const int row0 = blockIdx.x * 64;
    const int t = threadIdx.x;

    {
        const float4* in4 = (const float4*)in;
        float4* lds4 = (float4*)ldsA;
#pragma unroll
        for (int s = 0; s < 8; ++s) {
            int idx = t + s * 256;
            int r = idx >> 5;
            int grow = row0 + r;
            float4 v = make_float4(0.f, 0.f, 0.f, 0.f);
            if (grow < nrows) v = in4[(size_t)grow * 32 + (idx & 31)];
            lds4[idx] = v;
        }
    }
    __syncthreads();

    const int cg = t & 31, rg = t >> 5;
    float4 acc0[8], acc1[8];
#pragma unroll
    for (int i = 0; i < 8; ++i) {
        acc0[i] = make_float4(0.f, 0.f, 0.f, 0.f);
        if constexpr (CPT == 8) acc1[i] = make_float4(0.f, 0.f, 0.f, 0.f);
    }
    const float4* lds4 = (const float4*)ldsA;
    const float4* W4 = (const float4*)W;

    for (int k4 = 0; k4 < 32; ++k4) {
        float4 a[8];
#pragma unroll
        for (int i = 0; i < 8; ++i) a[i] = lds4[(rg * 8 + i) * 32 + k4];
#pragma unroll
        for (int kk = 0; kk < 4; ++kk) {
            const int k = k4 * 4 + kk;
            float4 b0 = W4[(k * COLS + cg * CPT) >> 2];
            float4 b1;
            if constexpr (CPT == 8) b1 = W4[((k * COLS + cg * CPT) >> 2) + 1];
#pragma unroll
            for (int i = 0; i < 8; ++i) {
                const float av = (kk == 0) ? a[i].x : (kk == 1) ? a[i].y
                               : (kk == 2) ? a[i].z : a[i].w;
                acc0[i].x = fmaf(av, b0.x, acc0[i].x);
                acc0[i].y = fmaf(av, b0.y, acc0[i].y);
                acc0[i].z = fmaf(av, b0.z, acc0[i].z);
                acc0[i].w = fmaf(av, b0.w, acc0[i].w);
                if constexpr (CPT == 8) {
                    acc1[i].x = fmaf(av, b1.x, acc1[i].x);
                    acc1[i].y = fmaf(av, b1.y, acc1[i].y);
                    acc1[i].z = fmaf(av, b1.z, acc1[i].z);
                    acc1[i].w = fmaf(av, b1.w, acc1[i].w);
                }
            }
        }
    }

#pragma unroll
    for (int i = 0; i < 8; ++i) {
        int grow = row0 + rg * 8 + i;
        if (grow < nrows) {
            float4* o4 = (float4*)(out + (size_t)grow * COLS + cg * CPT);
            o4[0] = acc0[i];
            if constexpr (CPT == 8) o4[1] = acc1[i];
        }
    }
}

// ---------------------------------------------------------------------------
// Wb prep: pack Wb (128x256, row-major [k][col]) into A-fragment-linear f16.
// WbF[((ks*16 + rt)*64 + lane)*8 + j] = f16(Wb[k][col]),
//   col = rt*16 + (lane&15), k = ks*32 + (lane>>4)*8 + j.
// A-frag load in the edge kernel is then a fully-coalesced 16B/lane read.
// ---------------------------------------------------------------------------
__global__ __launch_bounds__(256) void wb_prep_kernel(
    const float* __restrict__ Wb, _Float16* __restrict__ WbF)
{
    int id = blockIdx.x * 256 + threadIdx.x;
    if (id >= 128 * 256) return;
    int j  = id & 7;
    int l  = (id >> 3) & 63;
    int rt = (id >> 9) & 15;
    int ks = id >> 13;
    int col = rt * 16 + (l & 15);
    int k   = ks * 32 + (l >> 4) * 8 + j;
    WbF[id] = (_Float16)Wb[(size_t)k * 256 + col];
}

// ---------------------------------------------------------------------------
// Fused edge kernel, v2: barrier-free, LDS-free.
//   D = Wb^T (A-operand, f16) x IR (B-operand, f16 hi+lo 2-term split).
// Wave = 32 edges (2 N-tiles). Lane (arow=lane&15, kg=lane>>4) holds, per
// edge et: edge = w*32 + et*16 + arow; Wb-cols rt*16 + kg*4 + {0..3} in
// acc[rt][et] (verified C-layout: col=lane&15, row=kg*4+reg).
// Epilogue: float4 q/k gathers per rt; head h=(kg&1)*4+j; shfl_xor(32)
// combines kg<->kg^2; lanes kg<2 write pair_logits.
// ---------------------------------------------------------------------------
__device__ inline void split8(const float* __restrict__ p, f16x8& h, f16x8& l)
{
    float4 a = *(const float4*)p;
    float4 b = *(const float4*)(p + 4);
    float v[8] = {a.x, a.y, a.z, a.w, b.x, b.y, b.z, b.w};
#pragma unroll
    for (int j = 0; j < 8; ++j) {
        _Float16 hh = (_Float16)v[j];
        h[j] = hh;
        l[j] = (_Float16)(v[j] - (float)hh);
    }
}

__global__ __launch_bounds__(256, 2) void edge_logit_mfma_kernel(
    const float* __restrict__ ir, const _Float16* __restrict__ WbF,
    const float* __restrict__ qtab, const float* __restrict__ kvtab,
    const int* __restrict__ qidx, const int* __restrict__ kidx,
    const float* __restrict__ normalizer,
    float* __restrict__ pair_logits, int M)
{
    const int t = threadIdx.x;
    const int w = t >> 6, lane = t & 63;
    const int arow = lane & 15, kg = lane >> 4;
    const int row0 = blockIdx.x * 128 + w * 32;
    const int m0 = row0 + arow;
    const int m1 = m0 + 16;
    const int m0c = min(m0, M - 1), m1c = min(m1, M - 1);
    const int qi0 = qidx[m0c], ki0 = kidx[m0c];
    const int qi1 = qidx[m1c], ki1 = kidx[m1c];

    f32x4 acc[16][2];
#pragma unroll
    for (int rt = 0; rt < 16; ++rt) {
        acc[rt][0] = (f32x4){0.f, 0.f, 0.f, 0.f};
        acc[rt][1] = (f32x4){0.f, 0.f, 0.f, 0.f};
    }

    const float* ir0 = ir + (size_t)m0c * 128;
    const float* ir1 = ir + (size_t)m1c * 128;

#pragma unroll
    for (int ks = 0; ks < 4; ++ks) {
        const int k0 = ks * 32 + kg * 8;
        f16x8 bh0, bl0, bh1, bl1;
        split8(ir0 + k0, bh0, bl0);
        split8(ir1 + k0, bh1, bl1);
        const _Float16* ap = WbF + ((size_t)(ks * 16) * 64 + lane) * 8;
#pragma unroll
        for (int rt = 0; rt < 16; ++rt) {
            f16x8 ah = *(const f16x8*)(ap + (size_t)rt * 64 * 8);
            acc[rt][0] = __builtin_amdgcn_mfma_f32_16x16x32_f16(ah, bh0, acc[rt][0], 0, 0, 0);
            acc[rt][0] = __builtin_amdgcn_mfma_f32_16x16x32_f16(ah, bl0, acc[rt][0], 0, 0, 0);
            acc[rt][1] = __builtin_amdgcn_mfma_f32_16x16x32_f16(ah, bh1, acc[rt][1], 0, 0, 0);
            acc[rt][1] = __builtin_amdgcn_mfma_f32_16x16x32_f16(ah, bl1, acc[rt][1], 0, 0, 0);
        }
    }

    const float nvn = fminf(fmaxf(normalizer[0], 1.0f), 16.0f);
    const float invnorm = 1.0f / nvn;

    float h0[4] = {0.f, 0.f, 0.f, 0.f};
    float h1[4] = {0.f, 0.f, 0.f, 0.f};
    {
        const float* q0 = qtab + (size_t)qi0 * 128 + kg * 4;
        const float* k0p = kvtab + (size_t)ki0 * 256 + kg * 4;
#pragma unroll
        for (int rt = 0; rt < 8; ++rt) {
            float4 q4 = *(const float4*)(q0 + rt * 16);
            float4 k4 = *(const float4*)(k0p + rt * 16);
            f32x4 bm = acc[rt][0], ba = acc[rt + 8][0];
            h0[0] += q4.x * (fmaf(k4.x, bm[0], k4.x) + ba[0]);
            h0[1] += q4.y * (fmaf(k4.y, bm[1], k4.y) + ba[1]);
            h0[2] += q4.z * (fmaf(k4.z, bm[2], k4.z) + ba[2]);
            h0[3] += q4.w * (fmaf(k4.w, bm[3], k4.w) + ba[3]);
        }
    }
    {
        const float* q1 = qtab + (size_t)qi1 * 128 + kg * 4;
        const float* k1p = kvtab + (size_t)ki1 * 256 + kg * 4;
#pragma unroll
        for (int rt = 0; rt < 8; ++rt) {
            float4 q4 = *(const float4*)(q1 + rt * 16);
            float4 k4 = *(const float4*)(k1p + rt * 16);
            f32x4 bm = acc[rt][1], ba = acc[rt + 8][1];
            h1[0] += q4.x * (fmaf(k4.x, bm[0], k4.x) + ba[0]);
            h1[1] += q4.y * (fmaf(k4.y, bm[1], k4.y) + ba[1]);
            h1[2] += q4.z * (fmaf(k4.z, bm[2], k4.z) + ba[2]);
            h1[3] += q4.w * (fmaf(k4.w, bm[3], k4.w) + ba[3]);
        }
    }

    // combine kg with kg^2 (same heads, other half of the 16 d-positions)
#pragma unroll
    for (int j = 0; j < 4; ++j) {
        h0[j] += __shfl_xor(h0[j], 32);
        h1[j] += __shfl_xor(h1[j], 32);
    }

    if (kg == 0) {
        if (m0 < M)
            *(float4*)(pair_logits + (size_t)m0 * 8) =
                make_float4(h0[0] * invnorm, h0[1] * invnorm,
                            h0[2] * invnorm, h0[3] * invnorm);
        if (m1 < M)
            *(float4*)(pair_logits + (size_t)m1 * 8) =
                make_float4(h1[0] * invnorm, h1[1] * invnorm,
                            h1[2] * invnorm, h1[3] * invnorm);
    } else if (kg == 1) {
        if (m0 < M)
            *(float4*)(pair_logits + (size_t)m0 * 8 + 4) =
                make_float4(h0[0] * invnorm, h0[1] * invnorm,
                            h0[2] * invnorm, h0[3] * invnorm);
        if (m1 < M)
            *(float4*)(pair_logits + (size_t)m1 * 8 + 4) =
                make_float4(h1[0] * invnorm, h1[1] * invnorm,
                            h1[2] * invnorm, h1[3] * invnorm);
    }
}

// ---------------------------------------------------------------------------
// CSR build: histogram -> block scan -> placement
// ---------------------------------------------------------------------------
__global__ __launch_bounds__(256) void hist_kernel(
    const int* __restrict__ qidx, int* __restrict__ cnt, int M)
{
    int m = blockIdx.x * 256 + threadIdx.x;
    if (m < M) atomicAdd(&cnt[qidx[m]], 1);
}

__global__ __launch_bounds__(256) void scan_kernel(
    const int* __restrict__ cnt, int* __restrict__ rowptr,
    int* __restrict__ wptr, int N)
{
    __shared__ int sums[256];
    const int t = threadIdx.x;
    const int chunk = (N + 255) / 256;
    const int b = t * chunk;
    const int e = min(b + chunk, N);
    int s = 0;
    for (int i = b; i < e; ++i) s += cnt[i];
    sums[t] = s;
    __syncthreads();
    for (int off = 1; off < 256; off <<= 1) {
        int v = (t >= off) ? sums[t - off] : 0;
        __syncthreads();
        sums[t] += v;
        __syncthreads();
    }
    int run = (t == 0) ? 0 : sums[t - 1];
    for (int i = b; i < e; ++i) {
        rowptr[i] = run;
        wptr[i] = run;
        run += cnt[i];
    }
    if (t == 255) rowptr[N] = sums[255];
}

__global__ __launch_bounds__(256) void place_kernel(
    const int* __restrict__ qidx, int* __restrict__ wptr,
    int* __restrict__ csr, int M)
{
    int m = blockIdx.x * 256 + threadIdx.x;
    if (m < M) {
        int p = atomicAdd(&wptr[qidx[m]], 1);
        csr[p] = m;
    }
}

// ---------------------------------------------------------------------------
// Per-node softmax + weighted V aggregation, v2 (vectorized).
// One wave per node. Pass 1: 8 edges/iter (lane = edge-slot g x head h).
// Pass 2: 2 edges/iter; half-wave j=lane&31 owns channels j*4..+3 (float4 V),
// head per element = (j&1)*4 + r; halves combined via shfl_xor(32).
// ---------------------------------------------------------------------------
__global__ __launch_bounds__(256) void node_agg_kernel(
    const float* __restrict__ pl, const float* __restrict__ kvtab,
    const int* __restrict__ kidx, const int* __restrict__ rowptr,
    const int* __restrict__ csr, float* __restrict__ agg, int N)
{
    const int node = blockIdx.x * 4 + (threadIdx.x >> 6);
    if (node >= N) return;
    const int lane = threadIdx.x & 63;
    const int beg = rowptr[node], end = rowptr[node + 1];
    const int cnt = end - beg;

    // pass 1: exp-sum per head
    const int g = lane >> 3, h = lane & 7;
    float s = 0.f;
    for (int i = g; i < cnt; i += 8) {
        int m = csr[beg + i];
        s += __expf(pl[(size_t)m * 8 + h]);
    }
    s += __shfl_xor(s, 8);
    s += __shfl_xor(s, 16);
    s += __shfl_xor(s, 32);
    const float inv = 1.0f / s;   // valid for head h = lane&7 on every lane

    // pass 2: weighted V accumulate
    const int j = lane & 31;
    const int half = lane >> 5;
    const int hb = (j & 1) * 4;
    float4 inv4 = make_float4(__shfl(inv, hb), __shfl(inv, hb + 1),
                              __shfl(inv, hb + 2), __shfl(inv, hb + 3));
    float ax = 0.f, ay = 0.f, az = 0.f, aw = 0.f;
    for (int i = half; i < cnt; i += 2) {
        int m = csr[beg + i];
        float4 p4 = *(const float4*)(pl + (size_t)m * 8 + hb);
        float wx = __expf(p4.x) * inv4.x;
        float wy = __expf(p4.y) * inv4.y;
        float wz = __expf(p4.z) * inv4.z;
        float ww = __expf(p4.w) * inv4.w;
        const float4* vp = (const float4*)(kvtab + (size_t)kidx[m] * 256 + 128);
        float4 v4 = vp[j];
        ax = fmaf(wx, v4.x, ax);
        ay = fmaf(wy, v4.y, ay);
        az = fmaf(wz, v4.z, az);
        aw = fmaf(ww, v4.w, aw);
    }
    ax += __shfl_xor(ax, 32);
    ay += __shfl_xor(ay, 32);
    az += __shfl_xor(az, 32);
    aw += __shfl_xor(aw, 32);
    if (lane < 32)
        ((float4*)(agg + (size_t)node * 128))[j] = make_float4(ax, ay, az, aw);
}

// ---------------------------------------------------------------------------
extern "C" void kernel_launch(void* const* d_in, const int* in_sizes, int n_in,
                              void* d_out, int out_size, void* d_ws, size_t ws_size,
                              hipStream_t stream)
{
    const float* query = (const float*)d_in[0];
    const float* key   = (const float*)d_in[1];
    const float* ir    = (const float*)d_in[2];
    const int*   qidx  = (const int*)d_in[3];
    const int*   kidx  = (const int*)d_in[4];
    const float* Wq    = (const float*)d_in[5];
    const float* Wkv   = (const float*)d_in[6];
    const float* Wb    = (const float*)d_in[7];
    const float* Wo    = (const float*)d_in[8];
    const float* normalizer = (const float*)d_in[9];

    const int N = in_sizes[0] / HIDDEN;   // 50000
    const int M = in_sizes[3];            // 800000

    float* out_result  = (float*)d_out;                        // N*128
    float* pair_logits = (float*)d_out + (size_t)N * HIDDEN;   // M*8

    // qtab borrows the out_result region (dead until the final GEMM).
    float* qtab = out_result;

    // workspace layout: agg(N*128 f, cnt aliases its head) | kvtab(N*256 f)
    //                   | rowptr(N+1 i) | wptr(N i) | csr(M i)
    float* agg    = (float*)d_ws;
    int*   cnt    = (int*)d_ws;
    float* kvtab  = agg + (size_t)N * 128;
    int*   rowptr = (int*)(kvtab + (size_t)N * 256);
    int*   wptr   = rowptr + (N + 1);
    int*   csr    = wptr + N;

    // WbF (fragment-linear f16, 64 KB) parked mid-agg: past cnt's head
    // usage, dead after edge kernel; node_agg overwrites later.
    _Float16* WbF = (_Float16*)(agg + (size_t)N * 64);

    const int rgrid = (N + 63) / 64;
    const int mgrid = (M + 255) / 256;

    // Wb fragment pack (tiny)
    wb_prep_kernel<<<128, 256, 0, stream>>>(Wb, WbF);

    // CSR build
    hipMemsetAsync(cnt, 0, (size_t)N * sizeof(int), stream);
    hist_kernel<<<mgrid, 256, 0, stream>>>(qidx, cnt, M);
    scan_kernel<<<1, 256, 0, stream>>>(cnt, rowptr, wptr, N);
    place_kernel<<<mgrid, 256, 0, stream>>>(qidx, wptr, csr, M);

    // projections
    rowgemm_kernel<128><<<rgrid, 256, 0, stream>>>(query, Wq, qtab, N);
    rowgemm_kernel<256><<<rgrid, 256, 0, stream>>>(key, Wkv, kvtab, N);

    // fused b-GEMM (MFMA f16 2-term, barrier/LDS-free) + per-edge logits
    edge_logit_mfma_kernel<<<(M + 127) / 128, 256, 0, stream>>>(
        ir, WbF, qtab, kvtab, qidx, kidx, normalizer, pair_logits, M);

    // per-node softmax + V aggregation (no atomics)
    node_agg_kernel<<<(N + 3) / 4, 256, 0, stream>>>(
        pair_logits, kvtab, kidx, rowptr, csr, agg, N);

    // output projection
    rowgemm_kernel<128><<<rgrid, 256, 0, stream>>>(agg, Wo, out_result, N);
}